// Round 11
// baseline (243.815 us; speedup 1.0000x reference)
//
#include <hip/hip_runtime.h>
#include <hip/hip_bf16.h>

#define HEADS  16
#define DHEAD  64
#define BATCH  4
#define SEQ    2048
#define DIM    1024
#define KVROWS 2112   // 2049 (null + SEQ) padded up to multiple of 64
#define CSHIFT 24.0f  // static softmax shift (log2 domain); s' ~ N(0,1.44)

typedef __hip_bfloat16 bf16;
typedef __attribute__((ext_vector_type(8))) short s8v;   // 8 x bf16 (4 VGPRs)
typedef __attribute__((ext_vector_type(4))) short s4v;   // 4 x bf16
typedef __attribute__((ext_vector_type(4))) float f4v;   // MFMA accumulator

// async global->LDS, 16B per lane, dest = wave-uniform base + lane*16
__device__ __forceinline__ void gl_lds16(const void* g, void* l) {
  __builtin_amdgcn_global_load_lds(
      (const __attribute__((address_space(1))) unsigned int*)g,
      (__attribute__((address_space(3))) unsigned int*)l, 16, 0, 0);
}

// ---------------------------------------------------------------------------
// PREP kernel (r16, verified): convert + 3 weight transposes + kv null/tail
// fill in ONE launch (block-uniform decode; 256 threads each).
// ---------------------------------------------------------------------------
__global__ void prep_kernel(const float* __restrict__ x, bf16* __restrict__ xb,
                            const float* __restrict__ Wq,
                            const float* __restrict__ Wout,
                            const float* __restrict__ Wkv,
                            bf16* __restrict__ WqkvT, bf16* __restrict__ WoutT,
                            const float* __restrict__ null_kv,
                            bf16* __restrict__ kvbuf, bf16* __restrict__ kvbufT) {
  __shared__ bf16 tile[32][33];
  const int t = threadIdx.x;
  int bid = blockIdx.x;
  if (bid < 4096) {               // ---- convert x -> xb ----
    const size_t i = ((size_t)bid * 256 + t) * 8;
    const float4 a = *(const float4*)&x[i];
    const float4 b = *(const float4*)&x[i + 4];
    bf16 v[8] = {__float2bfloat16(a.x), __float2bfloat16(a.y),
                 __float2bfloat16(a.z), __float2bfloat16(a.w),
                 __float2bfloat16(b.x), __float2bfloat16(b.y),
                 __float2bfloat16(b.z), __float2bfloat16(b.w)};
    *(s8v*)&xb[i] = *(s8v*)v;
  } else if (bid < 6208) {        // ---- weight transposes ----
    bid -= 4096;
    const float* src; bf16* dst; int C, bx, by;
    if (bid < 1024)      { src = Wq;   dst = WqkvT;             C = DIM;   bx = bid & 31; by = bid >> 5; }
    else if (bid < 2048) { bid -= 1024; src = Wout; dst = WoutT; C = DIM;  bx = bid & 31; by = bid >> 5; }
    else                 { bid -= 2048; src = Wkv;  dst = WqkvT + DIM * DIM; C = DHEAD; bx = bid & 1; by = bid >> 1; }
    const int c0 = bx * 32, r0 = by * 32;
    const int tx = t & 31, ty = t >> 5;
#pragma unroll
    for (int i = 0; i < 32; i += 8)
      tile[ty + i][tx] = __float2bfloat16(src[(size_t)(r0 + ty + i) * C + c0 + tx]);
    __syncthreads();
#pragma unroll
    for (int i = 0; i < 32; i += 8)
      dst[(size_t)(c0 + ty + i) * DIM + r0 + tx] = tile[tx][ty + i];
  } else {                        // ---- kv null row + zero tail ----
    const int idx = (bid - 6208) * 256 + t;
    const int d = idx & 63;
    const int s = (idx >> 6) & 63;
    const int b = idx >> 12;
    const int row = (s == 0) ? 0 : 2048 + s;
    const bf16 v = (s == 0) ? __float2bfloat16(null_kv[d]) : __float2bfloat16(0.f);
    kvbuf [(size_t)(b * KVROWS + row) * DHEAD + d] = v;
    kvbufT[(size_t)(b * DHEAD + d) * KVROWS + row] = v;
  }
}

// ---------------------------------------------------------------------------
// Shared 2-phase BK=64 GEMM core (r14 structure, verified): double-buffered
// gl_lds16 staging, prefetch-next-before-compute, one barrier per K-tile.
// 128x128 tile, 4 waves (2x2, 64x64), 4x4 16x16x32 frags, bank swizzle in
// the per-lane GLOBAL address.
// ---------------------------------------------------------------------------
#define GEMM_CORE(A_, BT_, K_)                                                \
  __shared__ bf16 As[2 * 128 * 64];                                           \
  __shared__ bf16 Bs[2 * 128 * 64];                                           \
  const int m0 = blockIdx.x * 128, n0 = blockIdx.y * 128;                     \
  const int t = threadIdx.x;                                                  \
  const int w = t >> 6, l = t & 63, lr = l & 15, lq = l >> 4;                 \
  const int wm = (w & 1) * 64, wn = (w >> 1) * 64;                            \
  f4v acc[4][4] = {};                                                         \
  const int rowl = l >> 2;                                                    \
  const int cl = ((l & 3) ^ ((l >> 3) & 3)) * 8;                              \
  const bf16* gA0 = (A_)  + (size_t)(m0 + 32 * w + rowl) * (K_) + cl;         \
  const bf16* gA1 = (A_)  + (size_t)(m0 + 32 * w + 16 + rowl) * (K_) + cl;    \
  const bf16* gB0 = (BT_) + (size_t)(n0 + 32 * w + rowl) * (K_) + cl;         \
  const bf16* gB1 = (BT_) + (size_t)(n0 + 32 * w + 16 + rowl) * (K_) + cl;    \
  const int sw = lq ^ ((lr >> 1) & 3);                                        \
  STAGEG(0, 0);                                                               \
  __syncthreads();                                                            \
  int cur = 0;                                                                \
  for (int k0 = 0; k0 < (K_); k0 += 64) {                                     \
    if (k0 + 64 < (K_)) STAGEG(cur ^ 1, k0 + 64);                             \
    const s8v* As16 = (const s8v*)(As + cur * 8192);                          \
    const s8v* Bs16 = (const s8v*)(Bs + cur * 8192);                          \
    _Pragma("unroll")                                                         \
    for (int kw = 0; kw < 2; kw++) {                                          \
      s8v a[4], b[4];                                                         \
      _Pragma("unroll")                                                       \
      for (int mt = 0; mt < 4; mt++)                                          \
        a[mt] = As16[kw * 512 + (wm + mt * 16 + lr) * 4 + sw];                \
      _Pragma("unroll")                                                       \
      for (int ct = 0; ct < 4; ct++)                                          \
        b[ct] = Bs16[kw * 512 + (wn + ct * 16 + lr) * 4 + sw];                \
      _Pragma("unroll")                                                       \
      for (int mt = 0; mt < 4; mt++)                                          \
        _Pragma("unroll")                                                     \
        for (int ct = 0; ct < 4; ct++)                                        \
          acc[mt][ct] = __builtin_amdgcn_mfma_f32_16x16x32_bf16(              \
              a[mt], b[ct], acc[mt][ct], 0, 0, 0);                            \
    }                                                                         \
    __syncthreads();                                                          \
    cur ^= 1;                                                                 \
  }

#define STAGEG(bi, kk)                                                        \
  do {                                                                        \
    gl_lds16(gA0 + (kk),      As + (bi) * 8192 + (2 * w) * 512);              \
    gl_lds16(gA1 + (kk),      As + (bi) * 8192 + (2 * w + 1) * 512);          \
    gl_lds16(gB0 + (kk),      Bs + (bi) * 8192 + (2 * w) * 512);              \
    gl_lds16(gB1 + (kk),      Bs + (bi) * 8192 + (2 * w + 1) * 512);          \
    gl_lds16(gA0 + (kk) + 32, As + (bi) * 8192 + 4096 + (2 * w) * 512);       \
    gl_lds16(gA1 + (kk) + 32, As + (bi) * 8192 + 4096 + (2 * w + 1) * 512);   \
    gl_lds16(gB0 + (kk) + 32, Bs + (bi) * 8192 + 4096 + (2 * w) * 512);       \
    gl_lds16(gB1 + (kk) + 32, Bs + (bi) * 8192 + 4096 + (2 * w + 1) * 512);   \
  } while (0)

// ---------------------------------------------------------------------------
// Out GEMM: att @ WoutT -> fp32, 2-phase BK=64 core.
// ---------------------------------------------------------------------------
__global__ __launch_bounds__(256) void gemm_out_kernel(
    const bf16* __restrict__ A, const bf16* __restrict__ BT,
    float* __restrict__ C, int K) {
  GEMM_CORE(A, BT, K)
#pragma unroll
  for (int mt = 0; mt < 4; mt++)
#pragma unroll
    for (int ct = 0; ct < 4; ct++)
#pragma unroll
      for (int r = 0; r < 4; r++) {
        const int row = m0 + wm + mt * 16 + lq * 4 + r;
        const int col = n0 + wn + ct * 16 + lr;
        C[(size_t)row * DIM + col] = acc[mt][ct][r];
      }
}

// ---------------------------------------------------------------------------
// FUSED Q+KV GEMM (r15, verified): grid dim3(64,9). BT = WqkvT (rows
// 0..1023 = WqT, 1024..1087 = WkvT, 1088..1151 allocated garbage).
// y<8: q epilogue (alpha-scaled bf16). y==8: kv epilogue, wn==0 waves only.
// ---------------------------------------------------------------------------
__global__ __launch_bounds__(256) void gemm_qkv_kernel(
    const bf16* __restrict__ A, const bf16* __restrict__ BT,
    bf16* __restrict__ q, bf16* __restrict__ kvbuf, bf16* __restrict__ kvbufT,
    int K, float alpha) {
  GEMM_CORE(A, BT, K)
  if (blockIdx.y < 8) {
#pragma unroll
    for (int mt = 0; mt < 4; mt++)
#pragma unroll
      for (int ct = 0; ct < 4; ct++)
#pragma unroll
        for (int r = 0; r < 4; r++) {
          const int row = m0 + wm + mt * 16 + lq * 4 + r;
          const int col = n0 + wn + ct * 16 + lr;
          q[(size_t)row * DIM + col] = __float2bfloat16(acc[mt][ct][r] * alpha);
        }
  } else if (wn == 0) {   // kv block, waves 0-1: cols 0..63 of kv
#pragma unroll
    for (int mt = 0; mt < 4; mt++)
#pragma unroll
      for (int ct = 0; ct < 4; ct++)
#pragma unroll
        for (int r = 0; r < 4; r++) {
          const int m = m0 + wm + mt * 16 + lq * 4 + r;
          const int c = ct * 16 + lr;
          const int bb = m >> 11, jj = (m & 2047) + 1;
          const bf16 v = __float2bfloat16(acc[mt][ct][r]);
          kvbuf [(size_t)(bb * KVROWS + jj) * DHEAD + c] = v;
          kvbufT[(size_t)(bb * DHEAD + c) * KVROWS + jj] = v;
        }
  }
}

// ---------------------------------------------------------------------------
// Transposed flash attention — r18: 4 HEADS PER BLOCK (grid 1024 -> 512).
// Pipe decomposition at 83.5us (r17): exp2 ~34%, DS ~35%, VALU ~21%, MFMA
// ~23% — mixed-bound; only aggregate-work cuts help (r17 evidence). exp2/
// MFMA/VALU are algorithmic; staging/barriers/global-KV scale with BLOCK
// count. 4 heads/block halves all three (8448 block-tiles vs 16896). The
// verified r16/r17 tile body runs twice per staged tile (head-groups
// hg=0,1; st[2][4] live at a time keeps peak VGPR ~190 < 256 cliff -> 8
// waves/CU, 2 blocks/CU). Per-head DS reads unchanged. Differs from r9's
// failed pairing: per-staged-tile compute DOUBLES, so the register
// prefetch has 2x compute to hide under. Includes r17's dropped-last-tile
// + epilogue correction and r16's ones-MFMA row-sum.
// ---------------------------------------------------------------------------
__global__ __launch_bounds__(256) void attn_kernel(
    const bf16* __restrict__ q,    // [B*SEQ][DIM] (pre-scaled by 0.125*log2e)
    const bf16* __restrict__ kv,   // [B][KVROWS][64]
    const bf16* __restrict__ kvT,  // [B][64][KVROWS]
    bf16* __restrict__ o) {        // [B*SEQ][DIM]
  __shared__ bf16 kvs [64][68];    // 8.5 KB
  __shared__ bf16 kvsT[64][68];    // 8.5 KB
  __shared__ bf16 Ps[4][16][68];   // 8.5 KB (wave-local, reused per head)
  const int t = threadIdx.x, w = t >> 6, l = t & 63, lr = l & 15, lq = l >> 4;
  const int blk = blockIdx.x;                 // 512 = 32 qt x 4 hp x 4 b
  const int qt = 31 - (blk >> 4);             // longest q-tiles first
  const int rem = blk & 15, hp = rem >> 2, b = rem & 3;
  const int q0 = qt * 64;
  const int iw = q0 + w * 16 + lr;

  const bf16* qbase = q + ((size_t)(b * SEQ) + iw) * DIM + hp * 256;
  s8v qb[4][2];
#pragma unroll
  for (int hh = 0; hh < 4; hh++) {
    qb[hh][0] = *(const s8v*)&qbase[hh * 64 + lq * 8];
    qb[hh][1] = *(const s8v*)&qbase[hh * 64 + 32 + lq * 8];
  }

  f4v oaccT[4][4] = {};
  f4v lacc[4] = {};
  const short onebf = (short)0x3F80;
  const s8v ones = {onebf, onebf, onebf, onebf, onebf, onebf, onebf, onebf};

  const bf16* kvb  = kv  + (size_t)b * KVROWS * DHEAD;
  const bf16* kvTb = kvT + (size_t)b * DHEAD * KVROWS;
  const int jend = q0 + 64;        // r17: last tile dropped, fixed in epilogue
  const int srow = t >> 2, scol = (t & 3) * 16;

  // prefetch tile 0 into registers
  s8v rkv0 = *(const s8v*)&kvb[(size_t)srow * DHEAD + scol];
  s8v rkv1 = *(const s8v*)&kvb[(size_t)srow * DHEAD + scol + 8];
  s8v rkT0 = *(const s8v*)&kvTb[(size_t)srow * KVROWS + scol];
  s8v rkT1 = *(const s8v*)&kvTb[(size_t)srow * KVROWS + scol + 8];

  for (int j0 = 0; j0 < jend; j0 += 64) {
    __syncthreads();   // previous tile's readers done
    *(s8v*)&kvs[srow][scol]      = rkv0;
    *(s8v*)&kvs[srow][scol + 8]  = rkv1;
    *(s8v*)&kvsT[srow][scol]     = rkT0;
    *(s8v*)&kvsT[srow][scol + 8] = rkT1;
    __syncthreads();   // writes visible

    // issue next tile's loads (clamped; overlap with compute below)
    const int jn = min(j0 + 64, KVROWS - 64);
    rkv0 = *(const s8v*)&kvb[(size_t)(jn + srow) * DHEAD + scol];
    rkv1 = *(const s8v*)&kvb[(size_t)(jn + srow) * DHEAD + scol + 8];
    rkT0 = *(const s8v*)&kvTb[(size_t)srow * KVROWS + jn + scol];
    rkT1 = *(const s8v*)&kvTb[(size_t)srow * KVROWS + jn + scol + 8];

    const bool diag = (j0 + 62 > q0 + w * 16);  // wave-uniform

#pragma unroll
    for (int hg = 0; hg < 2; hg++) {
      // ---- S^T for this head-group (KV A-frags read once per group) ----
      f4v st[2][4];
#pragma unroll
      for (int jt = 0; jt < 4; jt++) {
        s8v a0 = *(const s8v*)&kvs[jt * 16 + lr][lq * 8];
        s8v a1 = *(const s8v*)&kvs[jt * 16 + lr][32 + lq * 8];
#pragma unroll
        for (int h2 = 0; h2 < 2; h2++) {
          const int hh = hg * 2 + h2;
          f4v z = {-CSHIFT, -CSHIFT, -CSHIFT, -CSHIFT};
          z = __builtin_amdgcn_mfma_f32_16x16x32_bf16(a0, qb[hh][0], z, 0, 0, 0);
          z = __builtin_amdgcn_mfma_f32_16x16x32_bf16(a1, qb[hh][1], z, 0, 0, 0);
          st[h2][jt] = z;
        }
      }

#pragma unroll
      for (int h2 = 0; h2 < 2; h2++) {
        const int hh = hg * 2 + h2;
        if (diag) {
#pragma unroll
          for (int jt = 0; jt < 4; jt++)
#pragma unroll
            for (int r = 0; r < 4; r++) {
              const int jg = j0 + jt * 16 + lq * 4 + r;
              if (jg > iw + 1) st[h2][jt][r] = -1e30f;
            }
        }
#pragma unroll
        for (int jt = 0; jt < 4; jt++)
#pragma unroll
          for (int r = 0; r < 4; r++)
            st[h2][jt][r] = exp2f(st[h2][jt][r]);

        // P^T -> Ps[w] (wave-local), b64 writes
#pragma unroll
        for (int jt = 0; jt < 4; jt++) {
          s4v pk;
#pragma unroll
          for (int r = 0; r < 4; r++) {
            bf16 h16 = __float2bfloat16(st[h2][jt][r]);
            pk[r] = *(short*)&h16;
          }
          *(s4v*)&Ps[w][lr][jt * 16 + lq * 4] = pk;
        }
        const s8v pb0 = *(const s8v*)&Ps[w][lr][lq * 8];
        const s8v pb1 = *(const s8v*)&Ps[w][lr][32 + lq * 8];

        // l row-sum on the MFMA pipe
        lacc[hh] = __builtin_amdgcn_mfma_f32_16x16x32_bf16(ones, pb0, lacc[hh], 0, 0, 0);
        lacc[hh] = __builtin_amdgcn_mfma_f32_16x16x32_bf16(ones, pb1, lacc[hh], 0, 0, 0);

#pragma unroll
        for (int dt = 0; dt < 4; dt++) {
          s8v a0 = *(const s8v*)&kvsT[dt * 16 + lr][lq * 8];
          s8v a1 = *(const s8v*)&kvsT[dt * 16 + lr][32 + lq * 8];
          oaccT[hh][dt] = __builtin_amdgcn_mfma_f32_16x16x32_bf16(a0, pb0, oaccT[hh][dt], 0, 0, 0);
          oaccT[hh][dt] = __builtin_amdgcn_mfma_f32_16x16x32_bf16(a1, pb1, oaccT[hh][dt], 0, 0, 0);
        }
      }
    }
  }

  // r17 correction: the dropped tile's single unmasked element
  // (i* = q0+63, j* = q0+64). Owned by lanes {15,31,47,63} of wave 3.
  if (w == 3 && lr == 15) {
    const bf16* kvrow = kvb + (size_t)(q0 + 64) * DHEAD;
#pragma unroll
    for (int hh = 0; hh < 4; hh++) {
      float s = 0.f;
#pragma unroll
      for (int e = 0; e < 8; e++) {
        short a0 = qb[hh][0][e], a1 = qb[hh][1][e];
        s += __bfloat162float(*(bf16*)&a0) * __bfloat162float(kvrow[lq * 8 + e]);
        s += __bfloat162float(*(bf16*)&a1) * __bfloat162float(kvrow[32 + lq * 8 + e]);
      }
      s += __shfl_xor(s, 16);   // lanes 15<->31, 47<->63 (all active)
      s += __shfl_xor(s, 32);   // lanes 15<->47, 31<->63
      const float p = exp2f(s - CSHIFT);
      lacc[hh][0] += p;         // epilogue reads only [0]
#pragma unroll
      for (int dt = 0; dt < 4; dt++)
#pragma unroll
        for (int r = 0; r < 4; r++)
          oaccT[hh][dt][r] += p * __bfloat162float(kvrow[dt * 16 + lq * 4 + r]);
    }
  }

  // epilogue: lacc[hh][0] = full row sum for q-row lr (ones-MFMA, no shfl)
#pragma unroll
  for (int hh = 0; hh < 4; hh++) {
    const float inv = 1.0f / lacc[hh][0];
#pragma unroll
    for (int dt = 0; dt < 4; dt++) {
      s4v pk;
#pragma unroll
      for (int r = 0; r < 4; r++) {
        bf16 h16 = __float2bfloat16(oaccT[hh][dt][r] * inv);
        pk[r] = *(short*)&h16;
      }
      *(s4v*)&Ps[w][lr][dt * 16 + lq * 4] = pk;  // Ps[w][i][d] = O
    }
    const int orow = l >> 2, od = (l & 3) * 16;
    s8v o0 = *(const s8v*)&Ps[w][orow][od];
    s8v o1 = *(const s8v*)&Ps[w][orow][od + 8];
    bf16* op = o + ((size_t)(b * SEQ) + q0 + w * 16 + orow) * DIM + hp * 256 + hh * 64 + od;
    *(s8v*)&op[0] = o0;
    *(s8v*)&op[8] = o1;
  }
}

// ---------------------------------------------------------------------------
// Inputs fp32, output fp32 (32 MB d_out). d_out staging: q(bf16)@0..16MB,
// kvbufT@16MB (1.03MB) — dead before final fp32 GEMM. ws 35.1MB: att@0 16MB
// (WqkvT aliases att rows 0..1151, dead after fused GEMM) | xb@16MB |
// WoutT@32MB | kvbuf@34MB.
// ---------------------------------------------------------------------------
extern "C" void kernel_launch(void* const* d_in, const int* in_sizes, int n_in,
                              void* d_out, int out_size, void* d_ws, size_t ws_size,
                              hipStream_t stream) {
  const float* x       = (const float*)d_in[0];
  const float* Wq      = (const float*)d_in[1];
  const float* Wkv     = (const float*)d_in[2];
  const float* null_kv = (const float*)d_in[3];
  const float* Wout    = (const float*)d_in[4];
  float* out = (float*)d_out;

  char* dob = (char*)d_out;
  bf16* q      = (bf16*)dob;                                // 16 MB
  bf16* kvbufT = (bf16*)(dob + (size_t)16 * 1024 * 1024);   // 1.03 MB
  char* p = (char*)d_ws;
  bf16* att    = (bf16*)p;
  bf16* xb     = (bf16*)(p + (size_t)16 * 1024 * 1024);
  bf16* WoutT  = (bf16*)(p + (size_t)32 * 1024 * 1024);
  bf16* kvbuf  = (bf16*)(p + (size_t)34 * 1024 * 1024);
  bf16* WqkvT  = att;   // rows 0..1023 WqT, 1024..1087 WkvT, 1088..1151 junk

  // convert + transposes + kv fill, one launch (4096 + 2112 + 64 blocks)
  prep_kernel<<<6272, 256, 0, stream>>>(x, xb, Wq, Wout, Wkv, WqkvT, WoutT,
                                        null_kv, kvbuf, kvbufT);

  // fused: q = x@Wq * scale (y<8) AND kv = x@Wkv dual-layout (y==8)
  gemm_qkv_kernel<<<dim3(64, 9), 256, 0, stream>>>(xb, WqkvT, q, kvbuf, kvbufT,
                                                   DIM, 0.125f * 1.44269504089f);

  // attention: 4 heads/block, 512 blocks, register-prefetch pipeline
  attn_kernel<<<32 * 4 * BATCH, 256, 0, stream>>>(q, kvbuf, kvbufT, att);

  // out = att @ Wout -> d_out fp32 (q, kvbufT dead)
  gemm_out_kernel<<<dim3(64, 8), 256, 0, stream>>>(att, WoutT, out, DIM);
}

// Round 12
// 224.022 us; speedup vs baseline: 1.0884x; 1.0884x over previous
//
#include <hip/hip_runtime.h>
#include <hip/hip_bf16.h>

#define HEADS  16
#define DHEAD  64
#define BATCH  4
#define SEQ    2048
#define DIM    1024
#define KVROWS 2112   // 2049 (null + SEQ) padded up to multiple of 64
#define CSHIFT 24.0f  // static softmax shift (log2 domain); s' ~ N(0,1.44)

typedef __hip_bfloat16 bf16;
typedef __attribute__((ext_vector_type(8))) short s8v;   // 8 x bf16 (4 VGPRs)
typedef __attribute__((ext_vector_type(4))) short s4v;   // 4 x bf16
typedef __attribute__((ext_vector_type(4))) float f4v;   // MFMA accumulator

// async global->LDS, 16B per lane, dest = wave-uniform base + lane*16
__device__ __forceinline__ void gl_lds16(const void* g, void* l) {
  __builtin_amdgcn_global_load_lds(
      (const __attribute__((address_space(1))) unsigned int*)g,
      (__attribute__((address_space(3))) unsigned int*)l, 16, 0, 0);
}

// ---------------------------------------------------------------------------
// PREP kernel (r16, verified): convert + 3 weight transposes + kv null/tail
// fill in ONE launch (block-uniform decode; 256 threads each).
// ---------------------------------------------------------------------------
__global__ void prep_kernel(const float* __restrict__ x, bf16* __restrict__ xb,
                            const float* __restrict__ Wq,
                            const float* __restrict__ Wout,
                            const float* __restrict__ Wkv,
                            bf16* __restrict__ WqkvT, bf16* __restrict__ WoutT,
                            const float* __restrict__ null_kv,
                            bf16* __restrict__ kvbuf, bf16* __restrict__ kvbufT) {
  __shared__ bf16 tile[32][33];
  const int t = threadIdx.x;
  int bid = blockIdx.x;
  if (bid < 4096) {               // ---- convert x -> xb ----
    const size_t i = ((size_t)bid * 256 + t) * 8;
    const float4 a = *(const float4*)&x[i];
    const float4 b = *(const float4*)&x[i + 4];
    bf16 v[8] = {__float2bfloat16(a.x), __float2bfloat16(a.y),
                 __float2bfloat16(a.z), __float2bfloat16(a.w),
                 __float2bfloat16(b.x), __float2bfloat16(b.y),
                 __float2bfloat16(b.z), __float2bfloat16(b.w)};
    *(s8v*)&xb[i] = *(s8v*)v;
  } else if (bid < 6208) {        // ---- weight transposes ----
    bid -= 4096;
    const float* src; bf16* dst; int C, bx, by;
    if (bid < 1024)      { src = Wq;   dst = WqkvT;             C = DIM;   bx = bid & 31; by = bid >> 5; }
    else if (bid < 2048) { bid -= 1024; src = Wout; dst = WoutT; C = DIM;  bx = bid & 31; by = bid >> 5; }
    else                 { bid -= 2048; src = Wkv;  dst = WqkvT + DIM * DIM; C = DHEAD; bx = bid & 1; by = bid >> 1; }
    const int c0 = bx * 32, r0 = by * 32;
    const int tx = t & 31, ty = t >> 5;
#pragma unroll
    for (int i = 0; i < 32; i += 8)
      tile[ty + i][tx] = __float2bfloat16(src[(size_t)(r0 + ty + i) * C + c0 + tx]);
    __syncthreads();
#pragma unroll
    for (int i = 0; i < 32; i += 8)
      dst[(size_t)(c0 + ty + i) * DIM + r0 + tx] = tile[tx][ty + i];
  } else {                        // ---- kv null row + zero tail ----
    const int idx = (bid - 6208) * 256 + t;
    const int d = idx & 63;
    const int s = (idx >> 6) & 63;
    const int b = idx >> 12;
    const int row = (s == 0) ? 0 : 2048 + s;
    const bf16 v = (s == 0) ? __float2bfloat16(null_kv[d]) : __float2bfloat16(0.f);
    kvbuf [(size_t)(b * KVROWS + row) * DHEAD + d] = v;
    kvbufT[(size_t)(b * DHEAD + d) * KVROWS + row] = v;
  }
}

// ---------------------------------------------------------------------------
// r19 GEMM core: 8-WAVE (512-thread) blocks on the same 128x128 tile,
// BK=64, 2-phase double-buffer (r14 schedule, verified). Rationale: ideal
// MFMA time ~7us/GEMM but measured ~40-55us; 512 blocks = 2/CU x 4 waves =
// only 8 waves/CU to hide staging latency (attn hides the same class of
// latency at 16 waves/CU). 8 waves/block -> 16 waves/CU, same LDS (64KB,
// 2 blocks/CU), same traffic, byte-identical LDS layout (staging chunk c =
// rows 16c..16c+15; was 2 chunks/wave, now 1). Wave grid 2Mx4N: wave tile
// 64x32, acc[4][2], 8 MFMA/kw. ds_read/MFMA formulas unchanged except
// wave-offset constants.
// ---------------------------------------------------------------------------
#define GEMM_CORE(A_, BT_, K_)                                                \
  __shared__ bf16 As[2 * 128 * 64];                                           \
  __shared__ bf16 Bs[2 * 128 * 64];                                           \
  const int m0 = blockIdx.x * 128, n0 = blockIdx.y * 128;                     \
  const int t = threadIdx.x;                                                  \
  const int w = t >> 6, l = t & 63, lr = l & 15, lq = l >> 4;                 \
  const int wr = (w >> 2) * 64, wc = (w & 3) * 32;                            \
  f4v acc[4][2] = {};                                                         \
  const int rowl = l >> 2;                                                    \
  const int cl = ((l & 3) ^ ((l >> 3) & 3)) * 8;                              \
  const bf16* gA0 = (A_)  + (size_t)(m0 + 16 * w + rowl) * (K_) + cl;         \
  const bf16* gB0 = (BT_) + (size_t)(n0 + 16 * w + rowl) * (K_) + cl;         \
  const int sw = lq ^ ((lr >> 1) & 3);                                        \
  STAGEG(0, 0);                                                               \
  __syncthreads();                                                            \
  int cur = 0;                                                                \
  for (int k0 = 0; k0 < (K_); k0 += 64) {                                     \
    if (k0 + 64 < (K_)) STAGEG(cur ^ 1, k0 + 64);                             \
    const s8v* As16 = (const s8v*)(As + cur * 8192);                          \
    const s8v* Bs16 = (const s8v*)(Bs + cur * 8192);                          \
    _Pragma("unroll")                                                         \
    for (int kw = 0; kw < 2; kw++) {                                          \
      s8v a[4], b[2];                                                         \
      _Pragma("unroll")                                                       \
      for (int mt = 0; mt < 4; mt++)                                          \
        a[mt] = As16[kw * 512 + (wr + mt * 16 + lr) * 4 + sw];                \
      _Pragma("unroll")                                                       \
      for (int ct = 0; ct < 2; ct++)                                          \
        b[ct] = Bs16[kw * 512 + (wc + ct * 16 + lr) * 4 + sw];                \
      _Pragma("unroll")                                                       \
      for (int mt = 0; mt < 4; mt++)                                          \
        _Pragma("unroll")                                                     \
        for (int ct = 0; ct < 2; ct++)                                        \
          acc[mt][ct] = __builtin_amdgcn_mfma_f32_16x16x32_bf16(              \
              a[mt], b[ct], acc[mt][ct], 0, 0, 0);                            \
    }                                                                         \
    __syncthreads();                                                          \
    cur ^= 1;                                                                 \
  }

// 512 threads: one gl_lds16 = 8KB = one [128 rows][32 cols] window.
// Wave w's 64 lanes cover rows 16w..16w+15 (dest base + w*512 bf16).
#define STAGEG(bi, kk)                                                        \
  do {                                                                        \
    gl_lds16(gA0 + (kk),      As + (bi) * 8192 + w * 512);                    \
    gl_lds16(gA0 + (kk) + 32, As + (bi) * 8192 + 4096 + w * 512);             \
    gl_lds16(gB0 + (kk),      Bs + (bi) * 8192 + w * 512);                    \
    gl_lds16(gB0 + (kk) + 32, Bs + (bi) * 8192 + 4096 + w * 512);             \
  } while (0)

// ---------------------------------------------------------------------------
// Out GEMM: att @ WoutT -> fp32, 8-wave 2-phase BK=64 core.
// ---------------------------------------------------------------------------
__global__ __launch_bounds__(512) void gemm_out_kernel(
    const bf16* __restrict__ A, const bf16* __restrict__ BT,
    float* __restrict__ C, int K) {
  GEMM_CORE(A, BT, K)
#pragma unroll
  for (int mt = 0; mt < 4; mt++)
#pragma unroll
    for (int ct = 0; ct < 2; ct++)
#pragma unroll
      for (int r = 0; r < 4; r++) {
        const int row = m0 + wr + mt * 16 + lq * 4 + r;
        const int col = n0 + wc + ct * 16 + lr;
        C[(size_t)row * DIM + col] = acc[mt][ct][r];
      }
}

// ---------------------------------------------------------------------------
// FUSED Q+KV GEMM (r15 logic, 8-wave): grid dim3(64,9). BT = WqkvT (rows
// 0..1023 = WqT, 1024..1087 = WkvT, 1088..1151 allocated garbage).
// y<8: q epilogue (alpha-scaled bf16). y==8: kv epilogue — waves with
// wc<64 cover kv cols 0..63; others discard.
// ---------------------------------------------------------------------------
__global__ __launch_bounds__(512) void gemm_qkv_kernel(
    const bf16* __restrict__ A, const bf16* __restrict__ BT,
    bf16* __restrict__ q, bf16* __restrict__ kvbuf, bf16* __restrict__ kvbufT,
    int K, float alpha) {
  GEMM_CORE(A, BT, K)
  if (blockIdx.y < 8) {
#pragma unroll
    for (int mt = 0; mt < 4; mt++)
#pragma unroll
      for (int ct = 0; ct < 2; ct++)
#pragma unroll
        for (int r = 0; r < 4; r++) {
          const int row = m0 + wr + mt * 16 + lq * 4 + r;
          const int col = n0 + wc + ct * 16 + lr;
          q[(size_t)row * DIM + col] = __float2bfloat16(acc[mt][ct][r] * alpha);
        }
  } else if (wc < 64) {   // kv block: waves covering cols 0..63
#pragma unroll
    for (int mt = 0; mt < 4; mt++)
#pragma unroll
      for (int ct = 0; ct < 2; ct++)
#pragma unroll
        for (int r = 0; r < 4; r++) {
          const int m = m0 + wr + mt * 16 + lq * 4 + r;
          const int c = wc + ct * 16 + lr;
          const int bb = m >> 11, jj = (m & 2047) + 1;
          const bf16 v = __float2bfloat16(acc[mt][ct][r]);
          kvbuf [(size_t)(bb * KVROWS + jj) * DHEAD + c] = v;
          kvbufT[(size_t)(bb * DHEAD + c) * KVROWS + jj] = v;
        }
  }
}

// ---------------------------------------------------------------------------
// Transposed flash attention — r17 EXACT (measured 83.5us, the verified
// attn local optimum). 2 heads/block, 1024 blocks, register-prefetch
// pipeline, ones-MFMA row-sum, dropped-last-tile + epilogue correction.
// Residency experiments closed: 4-head (r18, -21%), pairing (r9, -12%),
// split-KV (r11, null). DO NOT EDIT.
// ---------------------------------------------------------------------------
__global__ __launch_bounds__(256) void attn_kernel(
    const bf16* __restrict__ q,    // [B*SEQ][DIM] (pre-scaled by 0.125*log2e)
    const bf16* __restrict__ kv,   // [B][KVROWS][64]
    const bf16* __restrict__ kvT,  // [B][64][KVROWS]
    bf16* __restrict__ o) {        // [B*SEQ][DIM]
  __shared__ bf16 kvs [64][68];    // 8.5 KB
  __shared__ bf16 kvsT[64][68];    // 8.5 KB
  __shared__ bf16 Ps[4][16][68];   // 8.5 KB (wave-local, reused per head)
  const int t = threadIdx.x, w = t >> 6, l = t & 63, lr = l & 15, lq = l >> 4;
  const int blk = blockIdx.x;                 // 1024 = 32 qt x 8 hp x 4 b
  const int qt = 31 - (blk >> 5);             // longest q-tiles first
  const int rem = blk & 31, hp = rem >> 2, b = rem & 3;
  const int q0 = qt * 64;
  const int iw = q0 + w * 16 + lr;

  const bf16* qbase = q + ((size_t)(b * SEQ) + iw) * DIM + hp * 128;
  s8v qb[2][2];
#pragma unroll
  for (int hh = 0; hh < 2; hh++) {
    qb[hh][0] = *(const s8v*)&qbase[hh * 64 + lq * 8];
    qb[hh][1] = *(const s8v*)&qbase[hh * 64 + 32 + lq * 8];
  }

  f4v oaccT[2][4] = {};
  f4v lacc[2] = {};
  const short onebf = (short)0x3F80;
  const s8v ones = {onebf, onebf, onebf, onebf, onebf, onebf, onebf, onebf};

  const bf16* kvb  = kv  + (size_t)b * KVROWS * DHEAD;
  const bf16* kvTb = kvT + (size_t)b * DHEAD * KVROWS;
  const int jend = q0 + 64;        // last tile dropped, fixed in epilogue
  const int srow = t >> 2, scol = (t & 3) * 16;

  // prefetch tile 0 into registers
  s8v rkv0 = *(const s8v*)&kvb[(size_t)srow * DHEAD + scol];
  s8v rkv1 = *(const s8v*)&kvb[(size_t)srow * DHEAD + scol + 8];
  s8v rkT0 = *(const s8v*)&kvTb[(size_t)srow * KVROWS + scol];
  s8v rkT1 = *(const s8v*)&kvTb[(size_t)srow * KVROWS + scol + 8];

  for (int j0 = 0; j0 < jend; j0 += 64) {
    __syncthreads();   // previous tile's readers done
    *(s8v*)&kvs[srow][scol]      = rkv0;
    *(s8v*)&kvs[srow][scol + 8]  = rkv1;
    *(s8v*)&kvsT[srow][scol]     = rkT0;
    *(s8v*)&kvsT[srow][scol + 8] = rkT1;
    __syncthreads();   // writes visible

    // issue next tile's loads (clamped; overlap with compute below)
    const int jn = min(j0 + 64, KVROWS - 64);
    rkv0 = *(const s8v*)&kvb[(size_t)(jn + srow) * DHEAD + scol];
    rkv1 = *(const s8v*)&kvb[(size_t)(jn + srow) * DHEAD + scol + 8];
    rkT0 = *(const s8v*)&kvTb[(size_t)srow * KVROWS + jn + scol];
    rkT1 = *(const s8v*)&kvTb[(size_t)srow * KVROWS + jn + scol + 8];

    // S^T for both heads (KV A-frags read once)
    f4v st[2][4];
#pragma unroll
    for (int jt = 0; jt < 4; jt++) {
      s8v a0 = *(const s8v*)&kvs[jt * 16 + lr][lq * 8];
      s8v a1 = *(const s8v*)&kvs[jt * 16 + lr][32 + lq * 8];
#pragma unroll
      for (int hh = 0; hh < 2; hh++) {
        f4v z = {-CSHIFT, -CSHIFT, -CSHIFT, -CSHIFT};
        z = __builtin_amdgcn_mfma_f32_16x16x32_bf16(a0, qb[hh][0], z, 0, 0, 0);
        z = __builtin_amdgcn_mfma_f32_16x16x32_bf16(a1, qb[hh][1], z, 0, 0, 0);
        st[hh][jt] = z;
      }
    }

    const bool diag = (j0 + 62 > q0 + w * 16);  // wave-uniform
#pragma unroll
    for (int hh = 0; hh < 2; hh++) {
      if (diag) {
#pragma unroll
        for (int jt = 0; jt < 4; jt++)
#pragma unroll
          for (int r = 0; r < 4; r++) {
            const int jg = j0 + jt * 16 + lq * 4 + r;
            if (jg > iw + 1) st[hh][jt][r] = -1e30f;
          }
      }
#pragma unroll
      for (int jt = 0; jt < 4; jt++)
#pragma unroll
        for (int r = 0; r < 4; r++)
          st[hh][jt][r] = exp2f(st[hh][jt][r]);

      // P^T -> Ps[w] (wave-local), b64 writes
#pragma unroll
      for (int jt = 0; jt < 4; jt++) {
        s4v pk;
#pragma unroll
        for (int r = 0; r < 4; r++) {
          bf16 h16 = __float2bfloat16(st[hh][jt][r]);
          pk[r] = *(short*)&h16;
        }
        *(s4v*)&Ps[w][lr][jt * 16 + lq * 4] = pk;
      }
      const s8v pb0 = *(const s8v*)&Ps[w][lr][lq * 8];
      const s8v pb1 = *(const s8v*)&Ps[w][lr][32 + lq * 8];

      // l row-sum on the MFMA pipe (all-ones A => every acc row = col-sum)
      lacc[hh] = __builtin_amdgcn_mfma_f32_16x16x32_bf16(ones, pb0, lacc[hh], 0, 0, 0);
      lacc[hh] = __builtin_amdgcn_mfma_f32_16x16x32_bf16(ones, pb1, lacc[hh], 0, 0, 0);

#pragma unroll
      for (int dt = 0; dt < 4; dt++) {
        s8v a0 = *(const s8v*)&kvsT[dt * 16 + lr][lq * 8];
        s8v a1 = *(const s8v*)&kvsT[dt * 16 + lr][32 + lq * 8];
        oaccT[hh][dt] = __builtin_amdgcn_mfma_f32_16x16x32_bf16(a0, pb0, oaccT[hh][dt], 0, 0, 0);
        oaccT[hh][dt] = __builtin_amdgcn_mfma_f32_16x16x32_bf16(a1, pb1, oaccT[hh][dt], 0, 0, 0);
      }
    }
  }

  // correction: the dropped tile's single unmasked element
  // (i* = q0+63, j* = q0+64). Owned by lanes {15,31,47,63} of wave 3.
  if (w == 3 && lr == 15) {
    const bf16* kvrow = kvb + (size_t)(q0 + 64) * DHEAD;
#pragma unroll
    for (int hh = 0; hh < 2; hh++) {
      float s = 0.f;
#pragma unroll
      for (int e = 0; e < 8; e++) {
        short a0 = qb[hh][0][e], a1 = qb[hh][1][e];
        s += __bfloat162float(*(bf16*)&a0) * __bfloat162float(kvrow[lq * 8 + e]);
        s += __bfloat162float(*(bf16*)&a1) * __bfloat162float(kvrow[32 + lq * 8 + e]);
      }
      s += __shfl_xor(s, 16);   // lanes 15<->31, 47<->63 (all active)
      s += __shfl_xor(s, 32);   // lanes 15<->47, 31<->63
      const float p = exp2f(s - CSHIFT);
      lacc[hh][0] += p;         // epilogue reads only [0]
#pragma unroll
      for (int dt = 0; dt < 4; dt++)
#pragma unroll
        for (int r = 0; r < 4; r++)
          oaccT[hh][dt][r] += p * __bfloat162float(kvrow[dt * 16 + lq * 4 + r]);
    }
  }

  // epilogue: lacc[hh][0] = full row sum for q-row lr (ones-MFMA, no shfl)
#pragma unroll
  for (int hh = 0; hh < 2; hh++) {
    const float inv = 1.0f / lacc[hh][0];
#pragma unroll
    for (int dt = 0; dt < 4; dt++) {
      s4v pk;
#pragma unroll
      for (int r = 0; r < 4; r++) {
        bf16 h16 = __float2bfloat16(oaccT[hh][dt][r] * inv);
        pk[r] = *(short*)&h16;
      }
      *(s4v*)&Ps[w][lr][dt * 16 + lq * 4] = pk;  // Ps[w][i][d] = O
    }
    const int orow = l >> 2, od = (l & 3) * 16;
    s8v o0 = *(const s8v*)&Ps[w][orow][od];
    s8v o1 = *(const s8v*)&Ps[w][orow][od + 8];
    bf16* op = o + ((size_t)(b * SEQ) + q0 + w * 16 + orow) * DIM + hp * 128 + hh * 64 + od;
    *(s8v*)&op[0] = o0;
    *(s8v*)&op[8] = o1;
  }
}

// ---------------------------------------------------------------------------
// Inputs fp32, output fp32 (32 MB d_out). d_out staging: q(bf16)@0..16MB,
// kvbufT@16MB (1.03MB) — dead before final fp32 GEMM. ws 35.1MB: att@0 16MB
// (WqkvT aliases att rows 0..1151, dead after fused GEMM) | xb@16MB |
// WoutT@32MB | kvbuf@34MB.
// ---------------------------------------------------------------------------
extern "C" void kernel_launch(void* const* d_in, const int* in_sizes, int n_in,
                              void* d_out, int out_size, void* d_ws, size_t ws_size,
                              hipStream_t stream) {
  const float* x       = (const float*)d_in[0];
  const float* Wq      = (const float*)d_in[1];
  const float* Wkv     = (const float*)d_in[2];
  const float* null_kv = (const float*)d_in[3];
  const float* Wout    = (const float*)d_in[4];
  float* out = (float*)d_out;

  char* dob = (char*)d_out;
  bf16* q      = (bf16*)dob;                                // 16 MB
  bf16* kvbufT = (bf16*)(dob + (size_t)16 * 1024 * 1024);   // 1.03 MB
  char* p = (char*)d_ws;
  bf16* att    = (bf16*)p;
  bf16* xb     = (bf16*)(p + (size_t)16 * 1024 * 1024);
  bf16* WoutT  = (bf16*)(p + (size_t)32 * 1024 * 1024);
  bf16* kvbuf  = (bf16*)(p + (size_t)34 * 1024 * 1024);
  bf16* WqkvT  = att;   // rows 0..1023 WqT, 1024..1087 WkvT, 1088..1151 junk

  // convert + transposes + kv fill, one launch (4096 + 2112 + 64 blocks)
  prep_kernel<<<6272, 256, 0, stream>>>(x, xb, Wq, Wout, Wkv, WqkvT, WoutT,
                                        null_kv, kvbuf, kvbufT);

  // fused: q = x@Wq * scale (y<8) AND kv = x@Wkv dual-layout (y==8); 8-wave
  gemm_qkv_kernel<<<dim3(64, 9), 512, 0, stream>>>(xb, WqkvT, q, kvbuf, kvbufT,
                                                   DIM, 0.125f * 1.44269504089f);

  // attention: 2 heads/block, 1024 blocks, register-prefetch pipeline (r17)
  attn_kernel<<<32 * 8 * BATCH, 256, 0, stream>>>(q, kvbuf, kvbufT, att);

  // out = att @ Wout -> d_out fp32 (q, kvbufT dead); 8-wave
  gemm_out_kernel<<<dim3(64, 8), 512, 0, stream>>>(att, WoutT, out, DIM);
}